// Round 5
// baseline (518.575 us; speedup 1.0000x reference)
//
#include <hip/hip_runtime.h>
#include <stdint.h>

// Shapes: B=4, T=2048, D=1024, H=16, HD=64, K=4 templates, VOCAB=32000
// Pipeline:
//   cvt(x,Wqkv,Wout) -> bf16
//   {Q,K,V} = x @ Wqkv^T   (bf16 MFMA GEMM; Q pre-scaled by 0.125*log2e)
//   attn = causal_flash_attn (bf16 MFMA, log2 softmax, 128-row q-tiles,
//          reg-cached K/V frags, fused emb-gather epilogue)
//   out = y @ Wout^T + bout  (fp32 out)
// Memory: Q + xbf + weights in d_ws (40 MB); K,V live in d_out (32 MB scratch).

typedef __attribute__((ext_vector_type(8))) short s16x8;
typedef __attribute__((ext_vector_type(4))) short s16x4;
typedef __attribute__((ext_vector_type(4))) float f32x4;

static __device__ __forceinline__ unsigned short f32_bf16(float f) {
  union { float f; unsigned u; } v; v.f = f;
  unsigned r = v.u + 0x7fffu + ((v.u >> 16) & 1u);
  return (unsigned short)(r >> 16);
}
static __device__ __forceinline__ float bf16_f32(unsigned short h) {
  union { float f; unsigned u; } v; v.u = ((unsigned)h) << 16;
  return v.f;
}
static __device__ __forceinline__ float fexp2(float x) {
#if __has_builtin(__builtin_amdgcn_exp2f)
  return __builtin_amdgcn_exp2f(x);
#else
  return exp2f(x);
#endif
}

// ---------------------------------------------------------------- convert
__global__ __launch_bounds__(256) void cvt_f32_bf16_k(
    const float* __restrict__ in, unsigned short* __restrict__ out, int n8) {
  int i = blockIdx.x * 256 + threadIdx.x;
  if (i >= n8) return;
  const float4* p = (const float4*)(in + (long)i * 8);
  float4 a = p[0], b = p[1];
  s16x8 o;
  o[0] = (short)f32_bf16(a.x); o[1] = (short)f32_bf16(a.y);
  o[2] = (short)f32_bf16(a.z); o[3] = (short)f32_bf16(a.w);
  o[4] = (short)f32_bf16(b.x); o[5] = (short)f32_bf16(b.y);
  o[6] = (short)f32_bf16(b.z); o[7] = (short)f32_bf16(b.w);
  *(s16x8*)(out + (long)i * 8) = o;
}

// ---------------------------------------------------------------- GEMM
__device__ __forceinline__ void glds16(const void* g, void* l) {
  __builtin_amdgcn_global_load_lds(
      (const __attribute__((address_space(1))) void*)g,
      (__attribute__((address_space(3))) void*)l, 16, 0, 0);
}

// OUTMODE 1: f32 out + bias into C0 (row stride N)
// OUTMODE 2: bf16 split-qkv out, row stride 1024 (bn<8 Q [pre-scaled], <16 K, else V)
template <int OUTMODE>
__global__ __launch_bounds__(256) void gemm_bt(
    const unsigned short* __restrict__ A,   // [M][K] bf16
    const unsigned short* __restrict__ Bm,  // [N][K] bf16
    void* __restrict__ C0, void* __restrict__ C1, void* __restrict__ C2,
    const float* __restrict__ bias, int M, int N, int K) {
  __shared__ unsigned short Asl[128 * 32];
  __shared__ unsigned short Bsl[128 * 32];
  const int tid = threadIdx.x;
  const int l = tid & 63;
  const int w = tid >> 6;
  const int wr = w >> 1, wc = w & 1;
  const int bm = blockIdx.y, bn = blockIdx.x;

  f32x4 acc[4][4] = {};

  const unsigned short* Ag = A + (long)(bm * 128 + w * 16 + (l >> 2)) * K + (l & 3) * 8;
  const unsigned short* Bg = Bm + (long)(bn * 128 + w * 16 + (l >> 2)) * K + (l & 3) * 8;
  unsigned short* Al0 = &Asl[w * 512];
  unsigned short* Bl0 = &Bsl[w * 512];
  const int ro = (l & 15) * 32 + (l >> 4) * 8;

  for (int k0 = 0; k0 < K; k0 += 32) {
    __syncthreads();
    glds16(Ag + k0, Al0);
    glds16(Ag + 64 * K + k0, Al0 + 2048);
    glds16(Bg + k0, Bl0);
    glds16(Bg + 64 * K + k0, Bl0 + 2048);
    __syncthreads();
    s16x8 af[4], bfr[4];
#pragma unroll
    for (int i = 0; i < 4; ++i)
      af[i] = *(const s16x8*)&Asl[(wr * 64 + i * 16) * 32 + ro];
#pragma unroll
    for (int j = 0; j < 4; ++j)
      bfr[j] = *(const s16x8*)&Bsl[(wc * 64 + j * 16) * 32 + ro];
#pragma unroll
    for (int i = 0; i < 4; ++i)
#pragma unroll
      for (int j = 0; j < 4; ++j)
        acc[i][j] = __builtin_amdgcn_mfma_f32_16x16x32_bf16(af[i], bfr[j], acc[i][j], 0, 0, 0);
  }

  const int crow = bm * 128 + wr * 64 + (l >> 4) * 4;
  if (OUTMODE == 2) {
    unsigned short* C = (unsigned short*)(bn < 8 ? C0 : (bn < 16 ? C1 : C2));
    // Q pre-scaled by 1/sqrt(64)*log2(e) so attn softmax runs in exp2 domain
    const float qsc = (bn < 8) ? 0.18033688f : 1.0f;
    const int colb = (bn & 7) * 128 + wc * 64 + (l & 15);
#pragma unroll
    for (int i = 0; i < 4; ++i)
#pragma unroll
      for (int j = 0; j < 4; ++j)
#pragma unroll
        for (int r = 0; r < 4; ++r)
          C[(long)(crow + i * 16 + r) * 1024 + colb + j * 16] = f32_bf16(acc[i][j][r] * qsc);
  } else {
    float* C = (float*)C0;
    const int ccol = bn * 128 + wc * 64 + (l & 15);
#pragma unroll
    for (int i = 0; i < 4; ++i)
#pragma unroll
      for (int j = 0; j < 4; ++j) {
        float bv = bias[ccol + j * 16];
#pragma unroll
        for (int r = 0; r < 4; ++r)
          C[(long)(crow + i * 16 + r) * N + ccol + j * 16] = acc[i][j][r] + bv;
      }
  }
}

// ---------------------------------------------------------------- attention
// Q,K,V: [8192][1024] bf16, head h at cols h*64..h*64+64. Q pre-scaled.
// 16 q-tiles of 128 rows; block bx handles pair {bx, 15-bx} of head bh.
// Each wave: 2 q-frags (16 rows) per target. KVBLK=64 stages; K/V fragments
// read ONCE per stage into registers and shared by up to 4 frag-tile units.
// Work per block = 66 frag-units for every bx (perfect balance).

__global__ __launch_bounds__(256) void attn_k(
    const unsigned short* __restrict__ Qb, const unsigned short* __restrict__ Kb,
    const unsigned short* __restrict__ Vb, unsigned short* __restrict__ attn,
    const int* __restrict__ seq, const float* __restrict__ emb,
    const float* __restrict__ bsc) {
  __shared__ unsigned short Ksl[64 * 72];  // [kv][hd]
  __shared__ unsigned short Vtl[64 * 72];  // [hd][kv^swz]
  __shared__ unsigned short Psl[64 * 72];  // [q(wave-local)][kv]
  const int tid = threadIdx.x;
  const int l = tid & 63;
  const int w = tid >> 6;
  const int g = l >> 4;
  const int d15 = l & 15;
  const int bx = blockIdx.x;  // 0..7
  const int bh = blockIdx.y;  // 0..63
  const int b = bh >> 4, h = bh & 15;
  const int tok0 = b * 2048;
  const int qt_[2] = {15 - bx, bx};  // tgt 0 = B (long), tgt 1 = A (short)
  const int ntiles = 2 * qt_[0] + 2;
  const unsigned short* Qp = Qb + (long)tok0 * 1024 + h * 64;
  const unsigned short* Kp = Kb + (long)tok0 * 1024 + h * 64;
  const unsigned short* Vp = Vb + (long)tok0 * 1024 + h * 64;

  s16x8 qf[2][2][2];  // [tgt][fi][kc]
#pragma unroll
  for (int t = 0; t < 2; ++t)
#pragma unroll
    for (int fi = 0; fi < 2; ++fi) {
      const unsigned short* qr =
          Qp + (long)(qt_[t] * 128 + fi * 64 + w * 16 + d15) * 1024 + g * 8;
      qf[t][fi][0] = *(const s16x8*)qr;
      qf[t][fi][1] = *(const s16x8*)(qr + 32);
    }
  f32x4 o[2][2][4] = {};
  float m[2][2][4], lp[2][2][4];
#pragma unroll
  for (int t = 0; t < 2; ++t)
#pragma unroll
    for (int fi = 0; fi < 2; ++fi)
#pragma unroll
      for (int r = 0; r < 4; ++r) {
        m[t][fi][r] = -1e30f;
        lp[t][fi][r] = 0.f;
      }

  // staging: thread -> kv row rs_ (0..63), d cols c0..c0+15
  const int rs_ = tid >> 2;
  const int c0 = (tid & 3) * 16;
  const int vswz = rs_ ^ ((c0 >> 4) * 8);
  const unsigned short* Kg = Kp + (long)rs_ * 1024 + c0;
  const unsigned short* Vg = Vp + (long)rs_ * 1024 + c0;
  s16x8 kp0 = *(const s16x8*)Kg, kp1 = *(const s16x8*)(Kg + 8);
  s16x8 vp0 = *(const s16x8*)Vg, vp1 = *(const s16x8*)(Vg + 8);

  for (int it = 0; it < ntiles; ++it) {
    const int kv0 = it * 64;
    __syncthreads();
    *(s16x8*)&Ksl[rs_ * 72 + c0] = kp0;
    *(s16x8*)&Ksl[rs_ * 72 + c0 + 8] = kp1;
#pragma unroll
    for (int e = 0; e < 8; ++e) {
      Vtl[(c0 + e) * 72 + vswz] = (unsigned short)vp0[e];
      Vtl[(c0 + 8 + e) * 72 + vswz] = (unsigned short)vp1[e];
    }
    if (it + 1 < ntiles) {
      Kg += 65536; Vg += 65536;
      kp0 = *(const s16x8*)Kg; kp1 = *(const s16x8*)(Kg + 8);
      vp0 = *(const s16x8*)Vg; vp1 = *(const s16x8*)(Vg + 8);
    }
    __syncthreads();

    // cache K and V fragments once; reuse for all active frag-units
    s16x8 kf[8], vf[8];
#pragma unroll
    for (int st = 0; st < 4; ++st)
#pragma unroll
      for (int kc = 0; kc < 2; ++kc)
        kf[st * 2 + kc] = *(const s16x8*)&Ksl[(st * 16 + d15) * 72 + kc * 32 + g * 8];
#pragma unroll
    for (int kc2 = 0; kc2 < 2; ++kc2)
#pragma unroll
      for (int ct = 0; ct < 4; ++ct)
        vf[kc2 * 4 + ct] =
            *(const s16x8*)&Vtl[(ct * 16 + d15) * 72 + ((kc2 * 32 + g * 8) ^ (ct * 8))];

#pragma unroll
    for (int t = 0; t < 2; ++t) {
      const int qt = qt_[t];
#pragma unroll
      for (int fi = 0; fi < 2; ++fi) {
        const int lim = 2 * qt + fi;
        if (it > lim) continue;  // frag fully above this kv tile (or A done)
        const bool diag = (it == lim);
        f32x4 s[4] = {};
        __builtin_amdgcn_s_setprio(1);
#pragma unroll
        for (int st = 0; st < 4; ++st)
#pragma unroll
          for (int kc = 0; kc < 2; ++kc)
            s[st] = __builtin_amdgcn_mfma_f32_16x16x32_bf16(
                qf[t][fi][kc], kf[st * 2 + kc], s[st], 0, 0, 0);
        __builtin_amdgcn_s_setprio(0);
#pragma unroll
        for (int r = 0; r < 4; ++r) {
          const int qabs = qt * 128 + fi * 64 + w * 16 + g * 4 + r;
          float sv0 = s[0][r], sv1 = s[1][r], sv2 = s[2][r], sv3 = s[3][r];
          if (diag) {
            if (kv0 + d15 > qabs) sv0 = -1e30f;
            if (kv0 + 16 + d15 > qabs) sv1 = -1e30f;
            if (kv0 + 32 + d15 > qabs) sv2 = -1e30f;
            if (kv0 + 48 + d15 > qabs) sv3 = -1e30f;
          }
          float mx = fmaxf(fmaxf(sv0, sv1), fmaxf(sv2, sv3));
          mx = fmaxf(mx, __shfl_xor(mx, 1));
          mx = fmaxf(mx, __shfl_xor(mx, 2));
          mx = fmaxf(mx, __shfl_xor(mx, 4));
          mx = fmaxf(mx, __shfl_xor(mx, 8));
          const float mn = fmaxf(m[t][fi][r], mx);
          const float c = fexp2(m[t][fi][r] - mn);
          m[t][fi][r] = mn;
          const float p0 = fexp2(sv0 - mn), p1 = fexp2(sv1 - mn);
          const float p2 = fexp2(sv2 - mn), p3 = fexp2(sv3 - mn);
          unsigned short* pr = &Psl[(w * 16 + g * 4 + r) * 72 + d15];
          pr[0] = f32_bf16(p0); pr[16] = f32_bf16(p1);
          pr[32] = f32_bf16(p2); pr[48] = f32_bf16(p3);
          lp[t][fi][r] = lp[t][fi][r] * c + ((p0 + p1) + (p2 + p3));
#pragma unroll
          for (int ct = 0; ct < 4; ++ct) o[t][fi][ct][r] *= c;
        }
        // P store->read is wave-local (rows w*16..+15): DS in-order, no barrier
        __builtin_amdgcn_s_setprio(1);
#pragma unroll
        for (int kc2 = 0; kc2 < 2; ++kc2) {
          s16x8 pf = *(const s16x8*)&Psl[(w * 16 + d15) * 72 + kc2 * 32 + g * 8];
#pragma unroll
          for (int ct = 0; ct < 4; ++ct)
            o[t][fi][ct] = __builtin_amdgcn_mfma_f32_16x16x32_bf16(
                pf, vf[kc2 * 4 + ct], o[t][fi][ct], 0, 0, 0);
        }
        __builtin_amdgcn_s_setprio(0);
      }
    }
  }

  // epilogue: deferred l-reduce, normalize, fused emb gather-add, store
  const float sc = bsc[0];
  const int colbase = h * 64 + d15;
#pragma unroll
  for (int t = 0; t < 2; ++t)
#pragma unroll
    for (int fi = 0; fi < 2; ++fi) {
      const int tk0 = tok0 + qt_[t] * 128 + fi * 64 + w * 16 + g * 4;
      unsigned short* ap = attn + (long)tk0 * 1024 + colbase;
#pragma unroll
      for (int r = 0; r < 4; ++r) {
        float ls = lp[t][fi][r];
        ls += __shfl_xor(ls, 1); ls += __shfl_xor(ls, 2);
        ls += __shfl_xor(ls, 4); ls += __shfl_xor(ls, 8);
        const float inv = 1.0f / ls;
        const int* sq = seq + (long)(tk0 + r) * 4;
        const float* e0 = emb + (long)sq[0] * 1024 + colbase;
        const float* e1 = emb + (long)sq[1] * 1024 + colbase;
        const float* e2 = emb + (long)sq[2] * 1024 + colbase;
        const float* e3 = emb + (long)sq[3] * 1024 + colbase;
#pragma unroll
        for (int ct = 0; ct < 4; ++ct) {
          const int cc = ct * 16;
          float ev = (e0[cc] + e1[cc]) + (e2[cc] + e3[cc]);
          ap[(long)r * 1024 + cc] = f32_bf16(o[t][fi][ct][r] * inv + sc * ev);
        }
      }
    }
}

// ---------------------------------------------------------------- launch
extern "C" void kernel_launch(void* const* d_in, const int* in_sizes, int n_in,
                              void* d_out, int out_size, void* d_ws, size_t ws_size,
                              hipStream_t stream) {
  const float* x = (const float*)d_in[0];
  const int* seq = (const int*)d_in[1];
  const float* Wqkv = (const float*)d_in[2];
  const float* Wout = (const float*)d_in[3];
  const float* bout = (const float*)d_in[4];
  const float* emb = (const float*)d_in[5];
  const float* bsc = (const float*)d_in[6];

  uint8_t* ws = (uint8_t*)d_ws;
  unsigned short* xbf = (unsigned short*)ws;                  // 16MB, reused as y
  unsigned short* wqkvb = (unsigned short*)(ws + 16777216);   // 6MB
  unsigned short* woutb = (unsigned short*)(ws + 23068672);   // 2MB
  unsigned short* Qb = (unsigned short*)(ws + 25165824);      // 16MB
  unsigned short* Kb = (unsigned short*)d_out;                // scratch in d_out
  unsigned short* Vb = Kb + (long)8192 * 1024;

  cvt_f32_bf16_k<<<4096, 256, 0, stream>>>(x, xbf, 1048576);
  cvt_f32_bf16_k<<<1536, 256, 0, stream>>>(Wqkv, wqkvb, 393216);
  cvt_f32_bf16_k<<<512, 256, 0, stream>>>(Wout, woutb, 131072);

  gemm_bt<2><<<dim3(24, 64), 256, 0, stream>>>(xbf, wqkvb, Qb, Kb, Vb, nullptr,
                                               8192, 3072, 1024);
  attn_k<<<dim3(8, 64), 256, 0, stream>>>(Qb, Kb, Vb, xbf, seq, emb, bsc);
  gemm_bt<1><<<dim3(8, 64), 256, 0, stream>>>(xbf, woutb, d_out, nullptr, nullptr,
                                              bout, 8192, 1024, 1024);
}

// Round 6
// 421.349 us; speedup vs baseline: 1.2307x; 1.2307x over previous
//
#include <hip/hip_runtime.h>
#include <stdint.h>

// Shapes: B=4, T=2048, D=1024, H=16, HD=64, K=4 templates, VOCAB=32000
// Pipeline:
//   cvt(x,Wqkv,Wout) -> bf16
//   {Q,K,V} = x @ Wqkv^T   (bf16 MFMA GEMM, BK=64, XOR-swizzled staging)
//   attn = causal_flash_attn (round-4 structure: 64-row q-tiles, paired blocks)
//   out = y @ Wout^T + bout  (fp32 out)
// Memory: Q + xbf + weights in d_ws (40 MB); K,V live in d_out (32 MB scratch).

typedef __attribute__((ext_vector_type(8))) short s16x8;
typedef __attribute__((ext_vector_type(4))) short s16x4;
typedef __attribute__((ext_vector_type(4))) float f32x4;

static __device__ __forceinline__ unsigned short f32_bf16(float f) {
  union { float f; unsigned u; } v; v.f = f;
  unsigned r = v.u + 0x7fffu + ((v.u >> 16) & 1u);
  return (unsigned short)(r >> 16);
}
static __device__ __forceinline__ float bf16_f32(unsigned short h) {
  union { float f; unsigned u; } v; v.u = ((unsigned)h) << 16;
  return v.f;
}
static __device__ __forceinline__ float fexp2(float x) {
#if __has_builtin(__builtin_amdgcn_exp2f)
  return __builtin_amdgcn_exp2f(x);
#else
  return exp2f(x);
#endif
}

// ---------------------------------------------------------------- convert
__global__ __launch_bounds__(256) void cvt_f32_bf16_k(
    const float* __restrict__ in, unsigned short* __restrict__ out, int n8) {
  int i = blockIdx.x * 256 + threadIdx.x;
  if (i >= n8) return;
  const float4* p = (const float4*)(in + (long)i * 8);
  float4 a = p[0], b = p[1];
  s16x8 o;
  o[0] = (short)f32_bf16(a.x); o[1] = (short)f32_bf16(a.y);
  o[2] = (short)f32_bf16(a.z); o[3] = (short)f32_bf16(a.w);
  o[4] = (short)f32_bf16(b.x); o[5] = (short)f32_bf16(b.y);
  o[6] = (short)f32_bf16(b.z); o[7] = (short)f32_bf16(b.w);
  *(s16x8*)(out + (long)i * 8) = o;
}

// ---------------------------------------------------------------- GEMM
// C[M,N] = A[M,K]*B[N,K]^T, 128x128 tile, BK=64 (2 sub-steps of 32), 4 waves.
// Staging: global_load_lds w16, linear LDS [128][64], source pre-swizzled
// (chunk ^= row&7) so reads use chunk = c ^ (row&7). Halves barrier count
// vs BK=32 (the vmcnt(0)+barrier drain is the m97 structural stall).
__device__ __forceinline__ void glds16(const void* g, void* l) {
  __builtin_amdgcn_global_load_lds(
      (const __attribute__((address_space(1))) void*)g,
      (__attribute__((address_space(3))) void*)l, 16, 0, 0);
}

// OUTMODE 1: f32 out + bias into C0 (row stride N)
// OUTMODE 2: bf16 split-qkv out, row stride 1024 (bn<8 Q [pre-scaled], <16 K, else V)
template <int OUTMODE>
__global__ __launch_bounds__(256) void gemm_bt(
    const unsigned short* __restrict__ A,   // [M][K] bf16
    const unsigned short* __restrict__ Bm,  // [N][K] bf16
    void* __restrict__ C0, void* __restrict__ C1, void* __restrict__ C2,
    const float* __restrict__ bias, int M, int N, int K) {
  __shared__ unsigned short Asl[128 * 64];
  __shared__ unsigned short Bsl[128 * 64];
  const int tid = threadIdx.x;
  const int l = tid & 63;
  const int w = tid >> 6;
  const int wr = w >> 1, wc = w & 1;
  const int bm = blockIdx.y, bn = blockIdx.x;

  f32x4 acc[4][4] = {};

  // staging: issue j covers rows j*32 + w*8 + (l>>3), chunk (l&7)^(l>>3) of the
  // 64-col window (pre-swizzled source, linear LDS dest = lane*16B)
  const int srow = w * 8 + (l >> 3);
  const int swz = ((l & 7) ^ (l >> 3)) * 8;
  const unsigned short* Ag = A + (long)(bm * 128 + srow) * K + swz;
  const unsigned short* Bg = Bm + (long)(bn * 128 + srow) * K + swz;
  unsigned short* Al0 = &Asl[w * 512];
  unsigned short* Bl0 = &Bsl[w * 512];
  const int fr = l & 15, g = l >> 4;

  for (int k0 = 0; k0 < K; k0 += 64) {
    __syncthreads();
#pragma unroll
    for (int j = 0; j < 4; ++j) {
      glds16(Ag + (long)j * 32 * K + k0, Al0 + j * 2048);
      glds16(Bg + (long)j * 32 * K + k0, Bl0 + j * 2048);
    }
    __syncthreads();
#pragma unroll
    for (int kk = 0; kk < 2; ++kk) {
      const int ch = ((g + 4 * kk) ^ (fr & 7)) * 8;  // LDS chunk holding k-cols g*8+kk*32
      s16x8 af[4], bfr[4];
#pragma unroll
      for (int i = 0; i < 4; ++i)
        af[i] = *(const s16x8*)&Asl[(wr * 64 + i * 16 + fr) * 64 + ch];
#pragma unroll
      for (int j = 0; j < 4; ++j)
        bfr[j] = *(const s16x8*)&Bsl[(wc * 64 + j * 16 + fr) * 64 + ch];
#pragma unroll
      for (int i = 0; i < 4; ++i)
#pragma unroll
        for (int j = 0; j < 4; ++j)
          acc[i][j] = __builtin_amdgcn_mfma_f32_16x16x32_bf16(af[i], bfr[j], acc[i][j], 0, 0, 0);
    }
  }

  const int crow = bm * 128 + wr * 64 + (l >> 4) * 4;
  if (OUTMODE == 2) {
    unsigned short* C = (unsigned short*)(bn < 8 ? C0 : (bn < 16 ? C1 : C2));
    // Q pre-scaled by 1/sqrt(64)*log2(e) so attn softmax runs in exp2 domain
    const float qsc = (bn < 8) ? 0.18033688f : 1.0f;
    const int colb = (bn & 7) * 128 + wc * 64 + (l & 15);
#pragma unroll
    for (int i = 0; i < 4; ++i)
#pragma unroll
      for (int j = 0; j < 4; ++j)
#pragma unroll
        for (int r = 0; r < 4; ++r)
          C[(long)(crow + i * 16 + r) * 1024 + colb + j * 16] = f32_bf16(acc[i][j][r] * qsc);
  } else {
    float* C = (float*)C0;
    const int ccol = bn * 128 + wc * 64 + (l & 15);
#pragma unroll
    for (int i = 0; i < 4; ++i)
#pragma unroll
      for (int j = 0; j < 4; ++j) {
        float bv = bias[ccol + j * 16];
#pragma unroll
        for (int r = 0; r < 4; ++r)
          C[(long)(crow + i * 16 + r) * N + ccol + j * 16] = acc[i][j][r] + bv;
      }
  }
}

// ---------------------------------------------------------------- attention
// (round-4 version: 64-row q-tiles, block pairs {bx, 31-bx}, KVBLK=64,
//  log2 softmax, deferred l-reduce, fused emb-gather epilogue; 112 VGPR)
__device__ __forceinline__ void attn_tile(
    const unsigned short* __restrict__ Ksl, const unsigned short* __restrict__ Vtl,
    unsigned short* Psl, const s16x8* qf, f32x4* o, float* m, float* lpart,
    int qt0, int kv0, bool diag, int w, int g, int d15) {
  f32x4 s[4] = {};
  __builtin_amdgcn_s_setprio(1);
#pragma unroll
  for (int st = 0; st < 4; ++st)
#pragma unroll
    for (int kc = 0; kc < 2; ++kc) {
      s16x8 kf = *(const s16x8*)&Ksl[(st * 16 + d15) * 72 + kc * 32 + g * 8];
      s[st] = __builtin_amdgcn_mfma_f32_16x16x32_bf16(qf[kc], kf, s[st], 0, 0, 0);
    }
  __builtin_amdgcn_s_setprio(0);
#pragma unroll
  for (int r = 0; r < 4; ++r) {
    const int qabs = qt0 + w * 16 + g * 4 + r;
    float sv0 = s[0][r], sv1 = s[1][r], sv2 = s[2][r], sv3 = s[3][r];
    if (diag) {
      if (kv0 + d15 > qabs) sv0 = -1e30f;
      if (kv0 + 16 + d15 > qabs) sv1 = -1e30f;
      if (kv0 + 32 + d15 > qabs) sv2 = -1e30f;
      if (kv0 + 48 + d15 > qabs) sv3 = -1e30f;
    }
    float mx = fmaxf(fmaxf(sv0, sv1), fmaxf(sv2, sv3));
    mx = fmaxf(mx, __shfl_xor(mx, 1));
    mx = fmaxf(mx, __shfl_xor(mx, 2));
    mx = fmaxf(mx, __shfl_xor(mx, 4));
    mx = fmaxf(mx, __shfl_xor(mx, 8));
    const float mn = fmaxf(m[r], mx);
    const float c = fexp2(m[r] - mn);
    m[r] = mn;
    const float p0 = fexp2(sv0 - mn), p1 = fexp2(sv1 - mn);
    const float p2 = fexp2(sv2 - mn), p3 = fexp2(sv3 - mn);
    unsigned short* pr = &Psl[(w * 16 + g * 4 + r) * 72 + d15];
    pr[0] = f32_bf16(p0); pr[16] = f32_bf16(p1);
    pr[32] = f32_bf16(p2); pr[48] = f32_bf16(p3);
    lpart[r] = lpart[r] * c + ((p0 + p1) + (p2 + p3));
#pragma unroll
    for (int ct = 0; ct < 4; ++ct) o[ct][r] *= c;
  }
  __builtin_amdgcn_s_setprio(1);
#pragma unroll
  for (int kc2 = 0; kc2 < 2; ++kc2) {
    s16x8 pf = *(const s16x8*)&Psl[(w * 16 + d15) * 72 + kc2 * 32 + g * 8];
#pragma unroll
    for (int ct = 0; ct < 4; ++ct) {
      s16x8 vf = *(const s16x8*)&Vtl[(ct * 16 + d15) * 72 + ((kc2 * 32 + g * 8) ^ (ct * 8))];
      o[ct] = __builtin_amdgcn_mfma_f32_16x16x32_bf16(pf, vf, o[ct], 0, 0, 0);
    }
  }
  __builtin_amdgcn_s_setprio(0);
}

__global__ __launch_bounds__(256) void attn_k(
    const unsigned short* __restrict__ Qb, const unsigned short* __restrict__ Kb,
    const unsigned short* __restrict__ Vb, unsigned short* __restrict__ attn,
    const int* __restrict__ seq, const float* __restrict__ emb,
    const float* __restrict__ bsc) {
  __shared__ unsigned short Ksl[64 * 72];  // [kv][hd]
  __shared__ unsigned short Vtl[64 * 72];  // [hd][kv^swz]
  __shared__ unsigned short Psl[64 * 72];  // [q][kv]
  const int tid = threadIdx.x;
  const int l = tid & 63;
  const int w = tid >> 6;
  const int g = l >> 4;
  const int d15 = l & 15;
  const int bx = blockIdx.x;  // 0..15
  const int bh = blockIdx.y;  // 0..63
  const int b = bh >> 4, h = bh & 15;
  const int tok0 = b * 2048;
  const int qA = bx, qB = 31 - bx;
  const int nA = qA + 1, ntiles = qB + 1;
  const unsigned short* Qp = Qb + (long)tok0 * 1024 + h * 64;
  const unsigned short* Kp = Kb + (long)tok0 * 1024 + h * 64;
  const unsigned short* Vp = Vb + (long)tok0 * 1024 + h * 64;

  s16x8 qfA[2], qfB[2];
  {
    const unsigned short* qa = Qp + (long)(qA * 64 + w * 16 + d15) * 1024 + g * 8;
    qfA[0] = *(const s16x8*)qa;
    qfA[1] = *(const s16x8*)(qa + 32);
    const unsigned short* qbp = Qp + (long)(qB * 64 + w * 16 + d15) * 1024 + g * 8;
    qfB[0] = *(const s16x8*)qbp;
    qfB[1] = *(const s16x8*)(qbp + 32);
  }
  f32x4 oA[4] = {}, oB[4] = {};
  float mA[4], lA[4], mB[4], lB[4];
#pragma unroll
  for (int r = 0; r < 4; ++r) {
    mA[r] = -1e30f; lA[r] = 0.f; mB[r] = -1e30f; lB[r] = 0.f;
  }

  const int rs_ = tid >> 2;
  const int c0 = (tid & 3) * 16;
  const int vswz = rs_ ^ ((c0 >> 4) * 8);
  const unsigned short* Kg = Kp + (long)rs_ * 1024 + c0;
  const unsigned short* Vg = Vp + (long)rs_ * 1024 + c0;
  s16x8 kp0 = *(const s16x8*)Kg, kp1 = *(const s16x8*)(Kg + 8);
  s16x8 vp0 = *(const s16x8*)Vg, vp1 = *(const s16x8*)(Vg + 8);

  for (int it = 0; it < ntiles; ++it) {
    __syncthreads();
    *(s16x8*)&Ksl[rs_ * 72 + c0] = kp0;
    *(s16x8*)&Ksl[rs_ * 72 + c0 + 8] = kp1;
#pragma unroll
    for (int e = 0; e < 8; ++e) {
      Vtl[(c0 + e) * 72 + vswz] = (unsigned short)vp0[e];
      Vtl[(c0 + 8 + e) * 72 + vswz] = (unsigned short)vp1[e];
    }
    if (it + 1 < ntiles) {
      Kg += 65536; Vg += 65536;
      kp0 = *(const s16x8*)Kg; kp1 = *(const s16x8*)(Kg + 8);
      vp0 = *(const s16x8*)Vg; vp1 = *(const s16x8*)(Vg + 8);
    }
    __syncthreads();
    attn_tile(Ksl, Vtl, Psl, qfB, oB, mB, lB, qB * 64, it * 64, it == qB, w, g, d15);
    if (it < nA)
      attn_tile(Ksl, Vtl, Psl, qfA, oA, mA, lA, qA * 64, it * 64, it == qA, w, g, d15);
  }

#pragma unroll
  for (int r = 0; r < 4; ++r) {
    float sB = lB[r], sA = lA[r];
    sB += __shfl_xor(sB, 1); sB += __shfl_xor(sB, 2);
    sB += __shfl_xor(sB, 4); sB += __shfl_xor(sB, 8);
    sA += __shfl_xor(sA, 1); sA += __shfl_xor(sA, 2);
    sA += __shfl_xor(sA, 4); sA += __shfl_xor(sA, 8);
    lB[r] = sB; lA[r] = sA;
  }

  const float sc = bsc[0];
  const int colbase = h * 64 + d15;
  const int tB0 = tok0 + qB * 64 + w * 16 + g * 4;
  const int tA0 = tok0 + qA * 64 + w * 16 + g * 4;
  unsigned short* apB = attn + (long)tB0 * 1024 + colbase;
  unsigned short* apA = attn + (long)tA0 * 1024 + colbase;
#pragma unroll
  for (int r = 0; r < 4; ++r) {
    const float invB = 1.0f / lB[r];
    const float invA = 1.0f / lA[r];
    const int* sqB = seq + (long)(tB0 + r) * 4;
    const int* sqA = seq + (long)(tA0 + r) * 4;
    const float* eB0 = emb + (long)sqB[0] * 1024 + colbase;
    const float* eB1 = emb + (long)sqB[1] * 1024 + colbase;
    const float* eB2 = emb + (long)sqB[2] * 1024 + colbase;
    const float* eB3 = emb + (long)sqB[3] * 1024 + colbase;
    const float* eA0 = emb + (long)sqA[0] * 1024 + colbase;
    const float* eA1 = emb + (long)sqA[1] * 1024 + colbase;
    const float* eA2 = emb + (long)sqA[2] * 1024 + colbase;
    const float* eA3 = emb + (long)sqA[3] * 1024 + colbase;
#pragma unroll
    for (int ct = 0; ct < 4; ++ct) {
      const int cc = ct * 16;
      float embB = (eB0[cc] + eB1[cc]) + (eB2[cc] + eB3[cc]);
      float embA = (eA0[cc] + eA1[cc]) + (eA2[cc] + eA3[cc]);
      apB[(long)r * 1024 + cc] = f32_bf16(oB[ct][r] * invB + sc * embB);
      apA[(long)r * 1024 + cc] = f32_bf16(oA[ct][r] * invA + sc * embA);
    }
  }
}

// ---------------------------------------------------------------- launch
extern "C" void kernel_launch(void* const* d_in, const int* in_sizes, int n_in,
                              void* d_out, int out_size, void* d_ws, size_t ws_size,
                              hipStream_t stream) {
  const float* x = (const float*)d_in[0];
  const int* seq = (const int*)d_in[1];
  const float* Wqkv = (const float*)d_in[2];
  const float* Wout = (const float*)d_in[3];
  const float* bout = (const float*)d_in[4];
  const float* emb = (const float*)d_in[5];
  const float* bsc = (const float*)d_in[6];

  uint8_t* ws = (uint8_t*)d_ws;
  unsigned short* xbf = (unsigned short*)ws;                  // 16MB, reused as y
  unsigned short* wqkvb = (unsigned short*)(ws + 16777216);   // 6MB
  unsigned short* woutb = (unsigned short*)(ws + 23068672);   // 2MB
  unsigned short* Qb = (unsigned short*)(ws + 25165824);      // 16MB
  unsigned short* Kb = (unsigned short*)d_out;                // scratch in d_out
  unsigned short* Vb = Kb + (long)8192 * 1024;

  cvt_f32_bf16_k<<<4096, 256, 0, stream>>>(x, xbf, 1048576);
  cvt_f32_bf16_k<<<1536, 256, 0, stream>>>(Wqkv, wqkvb, 393216);
  cvt_f32_bf16_k<<<512, 256, 0, stream>>>(Wout, woutb, 131072);

  gemm_bt<2><<<dim3(24, 64), 256, 0, stream>>>(xbf, wqkvb, Qb, Kb, Vb, nullptr,
                                               8192, 3072, 1024);
  attn_k<<<dim3(16, 64), 256, 0, stream>>>(Qb, Kb, Vb, xbf, seq, emb, bsc);
  gemm_bt<1><<<dim3(8, 64), 256, 0, stream>>>(xbf, woutb, d_out, nullptr, nullptr,
                                              bout, 8192, 1024, 1024);
}